// Round 2
// baseline (228.091 us; speedup 1.0000x reference)
//
#include <hip/hip_runtime.h>

#define BSZ 8
#define LSEQ 8192
#define DDIM 256
#define CHUNK 16
#define WARM 48
#define DSTEPS 33          // double-steps: 24 warm + 8 valid + 1 output epilogue
#define CPB 16             // chains per block
#define VSTRIDE 4120       // per-batch V rows: 24 zero-pad + 4096 data
#define WSTRIDE 4096       // per-batch W rows

typedef float f32x4 __attribute__((ext_vector_type(4)));
typedef _Float16 h8 __attribute__((ext_vector_type(8)));
typedef _Float16 h4 __attribute__((ext_vector_type(4)));

// Step-doubled scan math (all products precomputed in fp32, rounded to fp16 once):
//   S_e     = S_{e-2} @ A2 + V_e            A2 = A@A
//   V_e     = x_{e-1} @ BA + x_e @ Bt       BA = B^T@A, Bt = B^T     (even seq rows)
//   O_e     = S_e @ Ct                      Ct = C^T
//   O_{e+1} = S_e @ ACt + W_{e+1}           ACt = A@C^T
//   W_m     = x_m @ BCt                     BCt = B^T@C^T            (odd seq rows)
// B-operand storage convention (proven): Mh[n*256 + k] = M[k][n].
// V/W layout: row-major compact rows, cols swizzled [row][g64*64 + l15*4 + ct]
// so a scan lane reads its 4 ct-values as ONE 8B load.

// ---------------- matrix prep (6 fp16 operand matrices + V zero pads) --------
__global__ void k_prep(const float* __restrict__ A, const float* __restrict__ B,
                       const float* __restrict__ C, _Float16* __restrict__ Bth,
                       _Float16* __restrict__ Cth, _Float16* __restrict__ A2h,
                       _Float16* __restrict__ BAh, _Float16* __restrict__ ACth,
                       _Float16* __restrict__ BCth, _Float16* __restrict__ V) {
  __shared__ float Acol[256], Crow[256];
  const int n = blockIdx.x, k = threadIdx.x;
  Acol[k] = A[k * 256 + n];   // A[j][n]
  Crow[k] = C[n * 256 + k];   // C[n][j]
  __syncthreads();
  float a2 = 0.f, ba = 0.f, act = 0.f, bct = 0.f;
  for (int j = 0; j < 256; ++j) {
    const float akj = A[k * 256 + j], bjk = B[j * 256 + k];
    const float ajn = Acol[j], cnj = Crow[j];
    a2 += akj * ajn;   // (A@A)[k][n]
    ba += bjk * ajn;   // (B^T@A)[k][n]
    act += akj * cnj;  // (A@C^T)[k][n]
    bct += bjk * cnj;  // (B^T@C^T)[k][n]
  }
  A2h[n * 256 + k] = (_Float16)a2;
  BAh[n * 256 + k] = (_Float16)ba;
  ACth[n * 256 + k] = (_Float16)act;
  BCth[n * 256 + k] = (_Float16)bct;
  Bth[n * 256 + k] = (_Float16)B[n * 256 + k];  // B^T[k][n] = B[n][k]
  Cth[n * 256 + k] = (_Float16)C[n * 256 + k];  // C^T[k][n] = C[n][k]
  if (n < BSZ) {  // zero the 24 warm-up pad rows at the head of batch n's V block
    _Float16* pz = V + (size_t)n * VSTRIDE * 256;
    for (int i = k; i < 24 * 256; i += 256) pz[i] = (_Float16)0.f;
  }
}

// ---------------- V (even rows, K=512) and W (odd rows, K=256) from x --------
// 512 blocks x 128 seq rows; x rows [R-1, R+127] staged once as fp16, split by
// parity into separate LDS arrays (keeps the proven stride-264 A-frag pattern).
__global__ __launch_bounds__(256, 2) void k_gemm_v(
    const float* __restrict__ x, const _Float16* __restrict__ Bth,
    const _Float16* __restrict__ BAh, const _Float16* __restrict__ BCth,
    _Float16* __restrict__ V, _Float16* __restrict__ W) {
  __shared__ __align__(16) _Float16 xe[64][264];  // even rows R+2i
  __shared__ __align__(16) _Float16 xo[65][264];  // odd rows R-1+2i
  const int tid = threadIdx.x, wv = tid >> 6, lane = tid & 63;
  const int l15 = lane & 15, q = lane >> 4;
  const int n0 = wv * 64;
  const size_t R = (size_t)blockIdx.x * 128;
  const int rb = (int)(R & (LSEQ - 1));
  const int bb = (int)(R >> 13);

  for (int i = 0; i < 33; ++i) {
    const int idx = i * 256 + tid;
    if (idx < 129 * 64) {
      const int j = idx >> 6, c4 = idx & 63;
      float4 v;
      if (j == 0 && rb == 0) v = make_float4(0.f, 0.f, 0.f, 0.f);  // x_{-1} = 0 at batch start
      else v = *(const float4*)(x + (R - 1 + j) * 256 + c4 * 4);
      h4 h;
      h[0] = (_Float16)v.x; h[1] = (_Float16)v.y; h[2] = (_Float16)v.z; h[3] = (_Float16)v.w;
      if (j & 1) *(h4*)&xe[(j - 1) >> 1][c4 * 4] = h;
      else       *(h4*)&xo[j >> 1][c4 * 4] = h;
    }
  }
  __syncthreads();

  h8 bf[4][8];
  // ---- W pass: W[R/2+i] = x_{R+1+2i} @ BCt ----
#pragma unroll
  for (int ct = 0; ct < 4; ++ct)
#pragma unroll
    for (int kb = 0; kb < 8; ++kb)
      bf[ct][kb] = *(const h8*)(BCth + (size_t)(n0 + ct * 16 + l15) * 256 + kb * 32 + q * 8);
  const size_t wbase = (size_t)bb * WSTRIDE + (rb >> 1);
#pragma unroll
  for (int rt = 0; rt < 4; ++rt) {
    f32x4 acc[4] = {};
#pragma unroll
    for (int kb = 0; kb < 8; ++kb) {
      h8 af = *(const h8*)&xo[1 + rt * 16 + l15][kb * 32 + q * 8];
#pragma unroll
      for (int ct = 0; ct < 4; ++ct)
        acc[ct] = __builtin_amdgcn_mfma_f32_16x16x32_f16(af, bf[ct][kb], acc[ct], 0, 0, 0);
    }
#pragma unroll
    for (int r = 0; r < 4; ++r) {
      h4 hv;
      hv[0] = (_Float16)acc[0][r]; hv[1] = (_Float16)acc[1][r];
      hv[2] = (_Float16)acc[2][r]; hv[3] = (_Float16)acc[3][r];
      *(h4*)(W + (wbase + rt * 16 + q * 4 + r) * 256 + n0 + l15 * 4) = hv;
    }
  }
  // ---- V pass: V[R/2+i] = x_{R-1+2i} @ BA + x_{R+2i} @ Bt ----
  f32x4 vacc[4][4] = {};
#pragma unroll
  for (int ct = 0; ct < 4; ++ct)
#pragma unroll
    for (int kb = 0; kb < 8; ++kb)
      bf[ct][kb] = *(const h8*)(BAh + (size_t)(n0 + ct * 16 + l15) * 256 + kb * 32 + q * 8);
#pragma unroll
  for (int rt = 0; rt < 4; ++rt)
#pragma unroll
    for (int kb = 0; kb < 8; ++kb) {
      h8 af = *(const h8*)&xo[rt * 16 + l15][kb * 32 + q * 8];
#pragma unroll
      for (int ct = 0; ct < 4; ++ct)
        vacc[rt][ct] = __builtin_amdgcn_mfma_f32_16x16x32_f16(af, bf[ct][kb], vacc[rt][ct], 0, 0, 0);
    }
#pragma unroll
  for (int ct = 0; ct < 4; ++ct)
#pragma unroll
    for (int kb = 0; kb < 8; ++kb)
      bf[ct][kb] = *(const h8*)(Bth + (size_t)(n0 + ct * 16 + l15) * 256 + kb * 32 + q * 8);
  const size_t vbase = (size_t)bb * VSTRIDE + 24 + (rb >> 1);
#pragma unroll
  for (int rt = 0; rt < 4; ++rt) {
#pragma unroll
    for (int kb = 0; kb < 8; ++kb) {
      h8 af = *(const h8*)&xe[rt * 16 + l15][kb * 32 + q * 8];
#pragma unroll
      for (int ct = 0; ct < 4; ++ct)
        vacc[rt][ct] = __builtin_amdgcn_mfma_f32_16x16x32_f16(af, bf[ct][kb], vacc[rt][ct], 0, 0, 0);
    }
#pragma unroll
    for (int r = 0; r < 4; ++r) {
      h4 hv;
      hv[0] = (_Float16)vacc[rt][0][r]; hv[1] = (_Float16)vacc[rt][1][r];
      hv[2] = (_Float16)vacc[rt][2][r]; hv[3] = (_Float16)vacc[rt][3][r];
      *(h4*)(V + (vbase + rt * 16 + q * 4 + r) * 256 + n0 + l15 * 4) = hv;
    }
  }
}

// ---------------- step-doubled fused scan + out-projection ----------------
// 33 barrier steps instead of 65. Valid steps: one af read set feeds 12 MFMAs
// (S via A2; O_e via Ct; O_{e+1} via ACt + W). O stores issued AFTER the
// barrier from live accumulators; running per-r pointers for V/W/O.
__global__ __launch_bounds__(256, 1) void k_scan(
    const _Float16* __restrict__ V, const _Float16* __restrict__ W,
    const _Float16* __restrict__ A2h, const _Float16* __restrict__ Cth,
    const _Float16* __restrict__ ACth, float* __restrict__ O) {
  __shared__ __align__(16) _Float16 st[2][CPB][264];  // state dbuf, proven layout
  const int tid = threadIdx.x, wv = tid >> 6, lane = tid & 63;
  const int l15 = lane & 15, q = lane >> 4;
  const int cw = wv * 64;
  const int b = blockIdx.x >> 5;
  const int c0 = (blockIdx.x & 31) * CPB;

  h8 a2f[4][8], ctf[4][8], actf[4][8];
#pragma unroll
  for (int ct = 0; ct < 4; ++ct)
#pragma unroll
    for (int kb = 0; kb < 8; ++kb) {
      const size_t mo = (size_t)(cw + ct * 16 + l15) * 256 + kb * 32 + q * 8;
      a2f[ct][kb] = *(const h8*)(A2h + mo);
      ctf[ct][kb] = *(const h8*)(Cth + mo);
      actf[ct][kb] = *(const h8*)(ACth + mo);
    }

  for (int i = tid; i < CPB * 264; i += 256) ((_Float16*)st[0])[i] = (_Float16)0.f;

  const _Float16* vp[4];
  const _Float16* wp[4];
  float* op[4];
#pragma unroll
  for (int r = 0; r < 4; ++r) {
    const int chain = c0 + q * 4 + r;
    // V padded row for e=-48: b*VSTRIDE + 24 + chain*8 - 24
    vp[r] = V + ((size_t)b * VSTRIDE + (size_t)chain * 8) * 256 + cw + l15 * 4;
    // W: prefetches at g2=24..31 read compact rows chain*8 + 0..7 (= W_1..W_15 odd)
    wp[r] = W + ((size_t)b * WSTRIDE + (size_t)chain * 8) * 256 + cw + l15 * 4;
    op[r] = O + ((size_t)b * LSEQ + (size_t)chain * CHUNK) * 256 + cw + l15;
  }

  h4 vc[4], vn[4] = {}, wc[4] = {}, wn[4] = {};
#pragma unroll
  for (int r = 0; r < 4; ++r) { vc[r] = *(const h4*)vp[r]; vp[r] += 256; }
  __syncthreads();  // drains st zero-init

  int cb = 0;
#pragma unroll 1
  for (int g2 = 0; g2 < DSTEPS; ++g2) {
    // prefetch next double-step's V/W fragments (never drained in-loop)
    if (g2 < 31) {
#pragma unroll
      for (int r = 0; r < 4; ++r) { vn[r] = *(const h4*)vp[r]; vp[r] += 256; }
    }
    if (g2 >= 24 && g2 < 32) {
#pragma unroll
      for (int r = 0; r < 4; ++r) { wn[r] = *(const h4*)wp[r]; wp[r] += 256; }
    }
    const bool doS = (g2 <= 31), doO = (g2 >= 25);
    f32x4 acc2[4], acc3[4];
    if (doS) {
      f32x4 acc[4];
#pragma unroll
      for (int ct = 0; ct < 4; ++ct) {
        acc[ct][0] = (float)vc[0][ct]; acc[ct][1] = (float)vc[1][ct];
        acc[ct][2] = (float)vc[2][ct]; acc[ct][3] = (float)vc[3][ct];
      }
      if (doO) {
#pragma unroll
        for (int ct = 0; ct < 4; ++ct) {
          acc2[ct] = (f32x4){0.f, 0.f, 0.f, 0.f};
          acc3[ct][0] = (float)wc[0][ct]; acc3[ct][1] = (float)wc[1][ct];
          acc3[ct][2] = (float)wc[2][ct]; acc3[ct][3] = (float)wc[3][ct];
        }
#pragma unroll
        for (int kb = 0; kb < 8; ++kb) {
          h8 af = *(const h8*)&st[cb][l15][kb * 32 + q * 8];
#pragma unroll
          for (int ct = 0; ct < 4; ++ct)
            acc[ct] = __builtin_amdgcn_mfma_f32_16x16x32_f16(af, a2f[ct][kb], acc[ct], 0, 0, 0);
#pragma unroll
          for (int ct = 0; ct < 4; ++ct)
            acc2[ct] = __builtin_amdgcn_mfma_f32_16x16x32_f16(af, ctf[ct][kb], acc2[ct], 0, 0, 0);
#pragma unroll
          for (int ct = 0; ct < 4; ++ct)
            acc3[ct] = __builtin_amdgcn_mfma_f32_16x16x32_f16(af, actf[ct][kb], acc3[ct], 0, 0, 0);
        }
      } else {
#pragma unroll
        for (int kb = 0; kb < 8; ++kb) {
          h8 af = *(const h8*)&st[cb][l15][kb * 32 + q * 8];
#pragma unroll
          for (int ct = 0; ct < 4; ++ct)
            acc[ct] = __builtin_amdgcn_mfma_f32_16x16x32_f16(af, a2f[ct][kb], acc[ct], 0, 0, 0);
        }
      }
#pragma unroll
      for (int ct = 0; ct < 4; ++ct)
#pragma unroll
        for (int r = 0; r < 4; ++r)
          st[cb ^ 1][q * 4 + r][cw + ct * 16 + l15] = (_Float16)acc[ct][r];
    } else {  // g2 == 32: emit O_14, O_15 from af = S_14 only
#pragma unroll
      for (int ct = 0; ct < 4; ++ct) {
        acc2[ct] = (f32x4){0.f, 0.f, 0.f, 0.f};
        acc3[ct][0] = (float)wc[0][ct]; acc3[ct][1] = (float)wc[1][ct];
        acc3[ct][2] = (float)wc[2][ct]; acc3[ct][3] = (float)wc[3][ct];
      }
#pragma unroll
      for (int kb = 0; kb < 8; ++kb) {
        h8 af = *(const h8*)&st[cb][l15][kb * 32 + q * 8];
#pragma unroll
        for (int ct = 0; ct < 4; ++ct)
          acc2[ct] = __builtin_amdgcn_mfma_f32_16x16x32_f16(af, ctf[ct][kb], acc2[ct], 0, 0, 0);
#pragma unroll
        for (int ct = 0; ct < 4; ++ct)
          acc3[ct] = __builtin_amdgcn_mfma_f32_16x16x32_f16(af, actf[ct][kb], acc3[ct], 0, 0, 0);
      }
    }
    // cross-wave hazard is LDS-only (st dbuf): wait LDS, barrier — NO vmem drain
    asm volatile("s_waitcnt lgkmcnt(0)" ::: "memory");
    __builtin_amdgcn_s_barrier();
    asm volatile("" ::: "memory");
    if (doO) {  // O_{e-2}, O_{e-1} stored post-barrier from live accumulators
#pragma unroll
      for (int r = 0; r < 4; ++r) {
        float* o = op[r];
#pragma unroll
        for (int ct = 0; ct < 4; ++ct) {
          o[ct * 16] = acc2[ct][r];
          o[256 + ct * 16] = acc3[ct][r];
        }
        op[r] += 512;
      }
    }
#pragma unroll
    for (int r = 0; r < 4; ++r) { vc[r] = vn[r]; wc[r] = wn[r]; }
    cb ^= 1;
  }
}

extern "C" void kernel_launch(void* const* d_in, const int* in_sizes, int n_in,
                              void* d_out, int out_size, void* d_ws, size_t ws_size,
                              hipStream_t stream) {
  const float* x = (const float*)d_in[0];
  const float* A = (const float*)d_in[1];
  const float* B = (const float*)d_in[2];
  const float* C = (const float*)d_in[3];

  char* ws = (char*)d_ws;
  _Float16* V = (_Float16*)ws;                       // 8*4120*512 = 16,875,520 B
  _Float16* W = (_Float16*)(ws + 17825792);          // 8*4096*512 = 16,777,216 B
  char* mats = ws + 34603008;
  _Float16* Bth = (_Float16*)(mats);
  _Float16* Cth = (_Float16*)(mats + 131072);
  _Float16* A2h = (_Float16*)(mats + 262144);
  _Float16* BAh = (_Float16*)(mats + 393216);
  _Float16* ACth = (_Float16*)(mats + 524288);
  _Float16* BCth = (_Float16*)(mats + 655360);
  float* out = (float*)d_out;

  hipLaunchKernelGGL(k_prep, dim3(256), dim3(256), 0, stream, A, B, C, Bth, Cth, A2h,
                     BAh, ACth, BCth, V);
  hipLaunchKernelGGL(k_gemm_v, dim3(512), dim3(256), 0, stream, x, Bth, BAh, BCth, V, W);
  hipLaunchKernelGGL(k_scan, dim3(256), dim3(256), 0, stream, V, W, A2h, Cth, ACth, out);
}